// Round 3
// baseline (271.899 us; speedup 1.0000x reference)
//
#include <hip/hip_runtime.h>
#include <math.h>

// BucketingBBoxCoder decode: B*N = 1,048,576 proposals.
// Per proposal: 28 f32 cls logits (4 sides x 7 buckets), 28 f32 offsets,
// 4 f32 proposal box -> 4 f32 bbox + 1 f32 conf.
//
// R1 strided (101us) / R2 256-thr tile+LDS (98us) / R3 1-wave tile (98us):
// duration invariant across structures; HBM 18%, VALU 13.5%, occ 44%,
// L3-warm same speed. Barrier-convoy theory falsified by R3.
// R4 (this): discriminate {per-wave latency-chain} vs {~2.8 TB/s fabric
// ceiling}. Each wave self-pipelines: 8 tiles of 64 proposals,
// global_load_lds (HBM->LDS direct, 15 x 1KB per tile: 7 cls + 7 off +
// 1 proposals), double-buffered LDS (2 x 15,360 B), counted
// s_waitcnt vmcnt(15) so the NEXT tile's 15 KB is in flight during the
// current tile's compute. No compiler-tracked loads in the loop.
// LDS layout is the natural [64][28] row-major (global_load_lds forbids
// padding); ds_read_b128 at 112 B lane stride -> 8 bank-slots per 8 lanes
// (<=2-way, free per m136).

#define WTILE 64   // proposals per tile == threads per block == one wave
#define ITERS 8    // tiles per block
// LDS words per buffer: cls 64*28=1792, off 1792, prop 64*4=256 -> 3840
#define W_CLS 0
#define W_OFF 1792
#define W_PRP 3584
#define W_BUF 3840

typedef float f32x4_v __attribute__((ext_vector_type(4)));

__device__ __forceinline__ void gl_lds16(const float* g, float* l) {
    // 16B per lane; LDS dest = uniform base + lane*16 (HW); global src per-lane.
    __builtin_amdgcn_global_load_lds(
        (const __attribute__((address_space(1))) unsigned int*)g,
        (__attribute__((address_space(3))) unsigned int*)l, 16, 0, 0);
}

__global__ __launch_bounds__(64) void bucketing_bbox_pipe_kernel(
    const float* __restrict__ proposals,
    const float* __restrict__ cls_preds,
    const float* __restrict__ offset_preds,
    float* __restrict__ out_bboxes,
    float* __restrict__ out_conf)
{
    __shared__ float lds[2][W_BUF];   // 2 x 15,360 B = 30,720 B -> 5 blocks/CU

    const int t = threadIdx.x;
    const size_t blk0 = (size_t)blockIdx.x * (ITERS * WTILE);

    // Issue one tile's 15 async HBM->LDS loads (each: 64 lanes x 16 B = 1 KB).
    // Per-lane global address (base + c*1024B + lane*16B); uniform LDS base.
    auto issue_tile = [&](int i, int b) {
        const size_t pbase = blk0 + (size_t)i * WTILE;
        const float* cg = cls_preds    + pbase * 28 + t * 4;
        const float* og = offset_preds + pbase * 28 + t * 4;
        const float* pg = proposals    + pbase * 4  + t * 4;
        float* lb = &lds[b][0];
#pragma unroll
        for (int c = 0; c < 7; ++c) gl_lds16(cg + c * 256, lb + W_CLS + c * 256);
#pragma unroll
        for (int c = 0; c < 7; ++c) gl_lds16(og + c * 256, lb + W_OFF + c * 256);
        gl_lds16(pg, lb + W_PRP);
    };

    // Prologue: tile 0 in flight.
    asm volatile("" ::: "memory");
    issue_tile(0, 0);

    for (int i = 0; i < ITERS; ++i) {
        if (i + 1 < ITERS) {
            asm volatile("" ::: "memory");       // pin issue block
            issue_tile(i + 1, (i + 1) & 1);
            // Wait until only the newest 15 (next tile) remain in flight:
            // drains tile i's loads + prior stores. Keeps pipeline full.
            asm volatile("s_waitcnt vmcnt(15)" ::: "memory");
        } else {
            asm volatile("s_waitcnt vmcnt(0)" ::: "memory");
        }

        const float* lb = &lds[i & 1][0];

        // ---- cls row: 7 x ds_read_b128, byte addr t*112 (16B-aligned) ----
        float cls[28];
        const float4* crow = reinterpret_cast<const float4*>(lb + W_CLS + t * 28);
#pragma unroll
        for (int k = 0; k < 7; ++k) reinterpret_cast<float4*>(cls)[k] = crow[k];
        float4 pr = reinterpret_cast<const float4*>(lb + W_PRP)[t];

        // ---- top-2 per side + softmax + confidence ----
        int   lab0s[4];
        float conf_sum = 0.0f;
#pragma unroll
        for (int s = 0; s < 4; ++s) {
            float best0 = cls[s * 7 + 0];
            float best1 = -INFINITY;
            int   lab0 = 0, lab1 = 0;
#pragma unroll
            for (int j = 1; j < 7; ++j) {
                float x = cls[s * 7 + j];
                bool gt0 = x > best0;
                bool gt1 = x > best1;
                // strict > with ascending j => lowest index wins ties (lax.top_k)
                best1 = gt0 ? best0 : (gt1 ? x : best1);
                lab1  = gt0 ? lab0  : (gt1 ? j : lab1);
                best0 = gt0 ? x : best0;
                lab0  = gt0 ? j : lab0;
            }
            float sum = 0.0f;
#pragma unroll
            for (int j = 0; j < 7; ++j) sum += __expf(cls[s * 7 + j] - best0);
            float inv = 1.0f / sum;
            lab0s[s] = lab0;
            float neighbor = fabsf((float)(lab0 - lab1)) - 1.0f;
            conf_sum += inv + __expf(best1 - best0) * inv * neighbor;
        }

        // ---- offset gather (4 scalar LDS reads, label-indexed) ----
        const float* orow = lb + W_OFF + t * 28;
        float osel0 = orow[0  + lab0s[0]];
        float osel1 = orow[7  + lab0s[1]];
        float osel2 = orow[14 + lab0s[2]];
        float osel3 = orow[21 + lab0s[3]];

        // ---- geometry + decode + clamp ----
        float cx = (pr.x + pr.z) * 0.5f;
        float cy = (pr.y + pr.w) * 0.5f;
        float pw = (pr.z - pr.x) * 3.0f;
        float ph = (pr.w - pr.y) * 3.0f;
        float px1 = cx - 0.5f * pw;
        float px2 = cx + 0.5f * pw;
        float py1 = cy - 0.5f * ph;
        float py2 = cy + 0.5f * ph;
        float bw = pw / 14.0f;
        float bh = ph / 14.0f;

        float x1 = px1 + (0.5f + (float)lab0s[0]) * bw - osel0 * bw;
        float x2 = px2 - (0.5f + (float)lab0s[1]) * bw - osel1 * bw;
        float y1 = py1 + (0.5f + (float)lab0s[2]) * bh - osel2 * bh;
        float y2 = py2 - (0.5f + (float)lab0s[3]) * bh - osel3 * bh;

        const float Wm = 1332.0f;  // W - 1
        const float Hm = 799.0f;   // H - 1
        x1 = fminf(fmaxf(x1, 0.0f), Wm);
        x2 = fminf(fmaxf(x2, 0.0f), Wm);
        y1 = fminf(fmaxf(y1, 0.0f), Hm);
        y2 = fminf(fmaxf(y2, 0.0f), Hm);

        const size_t gid = blk0 + (size_t)i * WTILE + t;
        f32x4_v bb = {x1, y1, x2, y2};
        __builtin_nontemporal_store(bb, reinterpret_cast<f32x4_v*>(out_bboxes) + gid);
        __builtin_nontemporal_store(conf_sum * 0.25f, out_conf + gid);
    }
}

// Tail fallback (per-thread; used only if total % (WTILE*ITERS) != 0).
__global__ __launch_bounds__(256) void bucketing_bbox_tail_kernel(
    const float* __restrict__ proposals,
    const float* __restrict__ cls_preds,
    const float* __restrict__ offset_preds,
    float* __restrict__ out_bboxes,
    float* __restrict__ out_conf,
    int start, int total)
{
    int i = start + blockIdx.x * blockDim.x + threadIdx.x;
    if (i >= total) return;

    float4 pr = reinterpret_cast<const float4*>(proposals)[i];
    float cls[28], offs[28];
    {
        const float4* cp = reinterpret_cast<const float4*>(cls_preds + (size_t)i * 28);
        const float4* op = reinterpret_cast<const float4*>(offset_preds + (size_t)i * 28);
#pragma unroll
        for (int k = 0; k < 7; ++k) reinterpret_cast<float4*>(cls)[k] = cp[k];
#pragma unroll
        for (int k = 0; k < 7; ++k) reinterpret_cast<float4*>(offs)[k] = op[k];
    }
    float cx = (pr.x + pr.z) * 0.5f;
    float cy = (pr.y + pr.w) * 0.5f;
    float pw = (pr.z - pr.x) * 3.0f;
    float ph = (pr.w - pr.y) * 3.0f;
    float px1 = cx - 0.5f * pw, px2 = cx + 0.5f * pw;
    float py1 = cy - 0.5f * ph, py2 = cy + 0.5f * ph;
    float bw = pw / 14.0f, bh = ph / 14.0f;

    int lab0s[4]; float offsel[4]; float conf_sum = 0.0f;
#pragma unroll
    for (int s = 0; s < 4; ++s) {
        float best0 = cls[s * 7], best1 = -INFINITY;
        int lab0 = 0, lab1 = 0;
        float osel = offs[s * 7];
#pragma unroll
        for (int j = 1; j < 7; ++j) {
            float x = cls[s * 7 + j], o = offs[s * 7 + j];
            bool gt0 = x > best0, gt1 = x > best1;
            best1 = gt0 ? best0 : (gt1 ? x : best1);
            lab1  = gt0 ? lab0  : (gt1 ? j : lab1);
            best0 = gt0 ? x : best0;
            lab0  = gt0 ? j : lab0;
            osel  = gt0 ? o : osel;
        }
        float sum = 0.0f;
#pragma unroll
        for (int j = 0; j < 7; ++j) sum += __expf(cls[s * 7 + j] - best0);
        float inv = 1.0f / sum;
        lab0s[s] = lab0; offsel[s] = osel;
        conf_sum += inv + __expf(best1 - best0) * inv * (fabsf((float)(lab0 - lab1)) - 1.0f);
    }
    float x1 = px1 + (0.5f + (float)lab0s[0]) * bw - offsel[0] * bw;
    float x2 = px2 - (0.5f + (float)lab0s[1]) * bw - offsel[1] * bw;
    float y1 = py1 + (0.5f + (float)lab0s[2]) * bh - offsel[2] * bh;
    float y2 = py2 - (0.5f + (float)lab0s[3]) * bh - offsel[3] * bh;
    x1 = fminf(fmaxf(x1, 0.0f), 1332.0f);
    x2 = fminf(fmaxf(x2, 0.0f), 1332.0f);
    y1 = fminf(fmaxf(y1, 0.0f), 799.0f);
    y2 = fminf(fmaxf(y2, 0.0f), 799.0f);
    reinterpret_cast<float4*>(out_bboxes)[i] = make_float4(x1, y1, x2, y2);
    out_conf[i] = conf_sum * 0.25f;
}

extern "C" void kernel_launch(void* const* d_in, const int* in_sizes, int n_in,
                              void* d_out, int out_size, void* d_ws, size_t ws_size,
                              hipStream_t stream) {
    const float* proposals    = (const float*)d_in[0];
    const float* cls_preds    = (const float*)d_in[1];
    const float* offset_preds = (const float*)d_in[2];

    int total = in_sizes[0] / 4;  // B*N proposals (1,048,576)

    float* out_bboxes = (float*)d_out;                       // total*4
    float* out_conf   = (float*)d_out + (size_t)total * 4;   // total

    const int per_block = WTILE * ITERS;          // 512
    int full_blocks = total / per_block;          // 2048 for this shape
    int rem = total - full_blocks * per_block;

    if (full_blocks > 0) {
        bucketing_bbox_pipe_kernel<<<full_blocks, WTILE, 0, stream>>>(
            proposals, cls_preds, offset_preds, out_bboxes, out_conf);
    }
    if (rem > 0) {
        int start = full_blocks * per_block;
        bucketing_bbox_tail_kernel<<<(rem + 255) / 256, 256, 0, stream>>>(
            proposals, cls_preds, offset_preds, out_bboxes, out_conf, start, total);
    }
}

// Round 4
// 243.976 us; speedup vs baseline: 1.1144x; 1.1144x over previous
//
#include <hip/hip_runtime.h>
#include <math.h>

// BucketingBBoxCoder decode: B*N = 1,048,576 proposals.
// Per proposal: 28 f32 cls logits (4 sides x 7 buckets), 28 f32 offsets,
// 4 f32 proposal box -> 4 f32 bbox + 1 f32 conf.
//
// R1 strided 101us / R2 256-thr tile 98us / R3 1-wave tile 98us /
// R4 gl_lds+vmcnt pipeline 109us: duration invariant across structures;
// no CU-side counter saturated. L3-warm dispatches (FETCH~0) also run 98us
// => reading 252 MB from Infinity Cache = 2.57 TB/s. Cold case: HBM 126 MB
// + IC fill 126 MB + IC read 126 MB at same ~2.7 TB/s port = 93us. Model:
// the IC port is the saturated server; every kernel queues behind it
// (53 MB in-flight / 2.78 TB/s = 19us queue delay = observed 21us wave life).
// R5 (this): NON-TEMPORAL loads for the 224 MB cls/offset streams (read
// exactly once -> never allocate in IC; evict-first). Reads become a pure
// HBM stream. Proposals (16 MB) stay cacheable. Outputs stay nontemporal.
// Predict: FETCH 123->245 MB, hbm 1.5->4.5-5.5 TB/s, dur 98->45-60us.
// Null (limit is L2<->CU): dur ~98, FETCH doubles -> wall is intra-XCD.

#define TILE 64     // proposals per block == threads per block == one wave
#define PAD_ROW 29  // 28 floats + 1 pad; odd stride -> conflict-free on 32 banks

typedef float f32x4_v __attribute__((ext_vector_type(4)));

__global__ __launch_bounds__(64) void bucketing_bbox_wave_kernel(
    const float* __restrict__ proposals,
    const float* __restrict__ cls_preds,
    const float* __restrict__ offset_preds,
    float* __restrict__ out_bboxes,
    float* __restrict__ out_conf)
{
    __shared__ float lds[TILE * PAD_ROW];  // 7,424 B

    const int t = threadIdx.x;
    const size_t base = (size_t)blockIdx.x * TILE;   // first proposal of tile
    const size_t gid = base + t;

    // ---- Coalesced global loads: 7 float4/thread/array, lane-contiguous ----
    // Non-temporal: these 224 MB are consumed exactly once per dispatch;
    // do NOT allocate them in L2/L3 (the IC port is the measured bottleneck).
    const f32x4_v* clsv = reinterpret_cast<const f32x4_v*>(cls_preds) + base * 7;
    const f32x4_v* offv = reinterpret_cast<const f32x4_v*>(offset_preds) + base * 7;
    f32x4_v creg[7], oreg[7];
#pragma unroll
    for (int k = 0; k < 7; ++k) creg[k] = __builtin_nontemporal_load(clsv + t + TILE * k);
#pragma unroll
    for (int k = 0; k < 7; ++k) oreg[k] = __builtin_nontemporal_load(offv + t + TILE * k);
    float4 pr = reinterpret_cast<const float4*>(proposals)[gid];

    // float4 index owned at iter k is f = t + 64k; proposal p = f/7, elem e = f%7.
    // Incremental: f += 64 => p += 9, e += 1 (64 = 9*7 + 1), wrap at 7.
    const int p0 = t / 7;
    const int e0 = t - p0 * 7;

    // ---- Phase 1: cls through LDS ----
    {
        int p = p0, e = e0;
#pragma unroll
        for (int k = 0; k < 7; ++k) {
            int a = p * PAD_ROW + 4 * e;
            lds[a + 0] = creg[k][0];
            lds[a + 1] = creg[k][1];
            lds[a + 2] = creg[k][2];
            lds[a + 3] = creg[k][3];
            p += 9; e += 1;
            if (e >= 7) { e -= 7; p += 1; }
        }
    }
    __syncthreads();  // intra-wave: hardware-released immediately

    float cls[28];
    const int rb = t * PAD_ROW;
#pragma unroll
    for (int j = 0; j < 28; ++j) cls[j] = lds[rb + j];  // stride 29: conflict-free
    __syncthreads();  // cls reads done; buffer free

    // ---- Phase 2 writes FIRST so they overlap the compute below ----
    {
        int p = p0, e = e0;
#pragma unroll
        for (int k = 0; k < 7; ++k) {
            int a = p * PAD_ROW + 4 * e;
            lds[a + 0] = oreg[k][0];
            lds[a + 1] = oreg[k][1];
            lds[a + 2] = oreg[k][2];
            lds[a + 3] = oreg[k][3];
            p += 9; e += 1;
            if (e >= 7) { e -= 7; p += 1; }
        }
    }

    // ---- top-2 per side + softmax probs + confidence (no LDS dependency) ----
    int   lab0s[4];
    float conf_sum = 0.0f;
#pragma unroll
    for (int s = 0; s < 4; ++s) {
        float best0 = cls[s * 7 + 0];
        float best1 = -INFINITY;
        int   lab0 = 0, lab1 = 0;
#pragma unroll
        for (int j = 1; j < 7; ++j) {
            float x = cls[s * 7 + j];
            bool gt0 = x > best0;
            bool gt1 = x > best1;
            // strict > with ascending j => lowest index wins ties (lax.top_k)
            best1 = gt0 ? best0 : (gt1 ? x : best1);
            lab1  = gt0 ? lab0  : (gt1 ? j : lab1);
            best0 = gt0 ? x : best0;
            lab0  = gt0 ? j : lab0;
        }
        float sum = 0.0f;
#pragma unroll
        for (int j = 0; j < 7; ++j) sum += __expf(cls[s * 7 + j] - best0);
        float inv = 1.0f / sum;
        float p0s = inv;
        float p1s = __expf(best1 - best0) * inv;

        lab0s[s] = lab0;
        float neighbor = fabsf((float)(lab0 - lab1)) - 1.0f;
        conf_sum += p0s + p1s * neighbor;
    }

    // ---- Proposal geometry (still no LDS dependency) ----
    float cx = (pr.x + pr.z) * 0.5f;
    float cy = (pr.y + pr.w) * 0.5f;
    float pw = (pr.z - pr.x) * 3.0f;
    float ph = (pr.w - pr.y) * 3.0f;
    float px1 = cx - 0.5f * pw;
    float px2 = cx + 0.5f * pw;
    float py1 = cy - 0.5f * ph;
    float py2 = cy + 0.5f * ph;
    float bw = pw / 14.0f;
    float bh = ph / 14.0f;

    __syncthreads();  // offsets staged

    float osel0 = lds[rb + 0  + lab0s[0]];
    float osel1 = lds[rb + 7  + lab0s[1]];
    float osel2 = lds[rb + 14 + lab0s[2]];
    float osel3 = lds[rb + 21 + lab0s[3]];

    float l_b = px1 + (0.5f + (float)lab0s[0]) * bw;
    float r_b = px2 - (0.5f + (float)lab0s[1]) * bw;
    float t_b = py1 + (0.5f + (float)lab0s[2]) * bh;
    float d_b = py2 - (0.5f + (float)lab0s[3]) * bh;

    float x1 = l_b - osel0 * bw;
    float x2 = r_b - osel1 * bw;
    float y1 = t_b - osel2 * bh;
    float y2 = d_b - osel3 * bh;

    const float Wm = 1332.0f;  // W - 1
    const float Hm = 799.0f;   // H - 1
    x1 = fminf(fmaxf(x1, 0.0f), Wm);
    x2 = fminf(fmaxf(x2, 0.0f), Wm);
    y1 = fminf(fmaxf(y1, 0.0f), Hm);
    y2 = fminf(fmaxf(y2, 0.0f), Hm);

    // Non-temporal: bbox output is never re-read; keep it out of the IC too.
    f32x4_v bb = {x1, y1, x2, y2};
    __builtin_nontemporal_store(bb, reinterpret_cast<f32x4_v*>(out_bboxes) + gid);
    out_conf[gid] = conf_sum * 0.25f;
}

// Tail fallback (per-thread strided; only used if total % TILE != 0 — it isn't
// for this problem's shape, but keep it correct for any size).
__global__ __launch_bounds__(256) void bucketing_bbox_tail_kernel(
    const float* __restrict__ proposals,
    const float* __restrict__ cls_preds,
    const float* __restrict__ offset_preds,
    float* __restrict__ out_bboxes,
    float* __restrict__ out_conf,
    int start, int total)
{
    int i = start + blockIdx.x * blockDim.x + threadIdx.x;
    if (i >= total) return;

    float4 pr = reinterpret_cast<const float4*>(proposals)[i];
    float cls[28], offs[28];
    {
        const float4* cp = reinterpret_cast<const float4*>(cls_preds + (size_t)i * 28);
        const float4* op = reinterpret_cast<const float4*>(offset_preds + (size_t)i * 28);
#pragma unroll
        for (int k = 0; k < 7; ++k) reinterpret_cast<float4*>(cls)[k] = cp[k];
#pragma unroll
        for (int k = 0; k < 7; ++k) reinterpret_cast<float4*>(offs)[k] = op[k];
    }
    float cx = (pr.x + pr.z) * 0.5f;
    float cy = (pr.y + pr.w) * 0.5f;
    float pw = (pr.z - pr.x) * 3.0f;
    float ph = (pr.w - pr.y) * 3.0f;
    float px1 = cx - 0.5f * pw, px2 = cx + 0.5f * pw;
    float py1 = cy - 0.5f * ph, py2 = cy + 0.5f * ph;
    float bw = pw / 14.0f, bh = ph / 14.0f;

    int lab0s[4]; float offsel[4]; float conf_sum = 0.0f;
#pragma unroll
    for (int s = 0; s < 4; ++s) {
        float best0 = cls[s * 7], best1 = -INFINITY;
        int lab0 = 0, lab1 = 0;
        float osel = offs[s * 7];
#pragma unroll
        for (int j = 1; j < 7; ++j) {
            float x = cls[s * 7 + j], o = offs[s * 7 + j];
            bool gt0 = x > best0, gt1 = x > best1;
            best1 = gt0 ? best0 : (gt1 ? x : best1);
            lab1  = gt0 ? lab0  : (gt1 ? j : lab1);
            best0 = gt0 ? x : best0;
            lab0  = gt0 ? j : lab0;
            osel  = gt0 ? o : osel;
        }
        float sum = 0.0f;
#pragma unroll
        for (int j = 0; j < 7; ++j) sum += __expf(cls[s * 7 + j] - best0);
        float inv = 1.0f / sum;
        lab0s[s] = lab0; offsel[s] = osel;
        conf_sum += inv + __expf(best1 - best0) * inv * (fabsf((float)(lab0 - lab1)) - 1.0f);
    }
    float x1 = px1 + (0.5f + (float)lab0s[0]) * bw - offsel[0] * bw;
    float x2 = px2 - (0.5f + (float)lab0s[1]) * bw - offsel[1] * bw;
    float y1 = py1 + (0.5f + (float)lab0s[2]) * bh - offsel[2] * bh;
    float y2 = py2 - (0.5f + (float)lab0s[3]) * bh - offsel[3] * bh;
    x1 = fminf(fmaxf(x1, 0.0f), 1332.0f);
    x2 = fminf(fmaxf(x2, 0.0f), 1332.0f);
    y1 = fminf(fmaxf(y1, 0.0f), 799.0f);
    y2 = fminf(fmaxf(y2, 0.0f), 799.0f);
    reinterpret_cast<float4*>(out_bboxes)[i] = make_float4(x1, y1, x2, y2);
    out_conf[i] = conf_sum * 0.25f;
}

extern "C" void kernel_launch(void* const* d_in, const int* in_sizes, int n_in,
                              void* d_out, int out_size, void* d_ws, size_t ws_size,
                              hipStream_t stream) {
    const float* proposals    = (const float*)d_in[0];
    const float* cls_preds    = (const float*)d_in[1];
    const float* offset_preds = (const float*)d_in[2];

    int total = in_sizes[0] / 4;  // B*N proposals (1,048,576)

    float* out_bboxes = (float*)d_out;                       // total*4
    float* out_conf   = (float*)d_out + (size_t)total * 4;   // total

    int full_tiles = total / TILE;   // 16,384 for this shape
    int rem = total - full_tiles * TILE;

    if (full_tiles > 0) {
        bucketing_bbox_wave_kernel<<<full_tiles, TILE, 0, stream>>>(
            proposals, cls_preds, offset_preds, out_bboxes, out_conf);
    }
    if (rem > 0) {
        int start = full_tiles * TILE;
        bucketing_bbox_tail_kernel<<<(rem + 255) / 256, 256, 0, stream>>>(
            proposals, cls_preds, offset_preds, out_bboxes, out_conf, start, total);
    }
}

// Round 5
// 239.181 us; speedup vs baseline: 1.1368x; 1.0200x over previous
//
#include <hip/hip_runtime.h>
#include <math.h>

// BucketingBBoxCoder decode: B*N = 1,048,576 proposals.
// Per proposal: 28 f32 cls logits (4 sides x 7 buckets), 28 f32 offsets,
// 4 f32 proposal box -> 4 f32 bbox + 1 f32 conf.
//
// R1 strided 101us / R2 256-thr tile 98us / R3 1-wave tile 98us /
// R4 gl_lds+vmcnt pipeline 109us: invariant ~98us, no CU counter saturated.
// Diagnosis: Infinity-Cache port saturated at ~2.7 TB/s — the 224 MB
// read-once stream was allocating into L3 (fill + read = 2x port traffic).
// R5: nontemporal cls/offset loads -> kernel fell below the 68us harness
// memsets (was 98us); harness dur 262->244us. Theory confirmed.
// Calibration: fillBufferAligned streams at 6.9 TB/s. Byte floor:
// 252 MB read + 21 MB write = 273 MB -> ~40-43us.
// R6 (this): 100% non-temporal — proposals loads (16 MB) and conf store
// (4 MB) also nt, so NO access allocates in the IC. Pure HBM stream.
// Predict: kernel ~48-55us, FETCH ~245 MB, WRITE ~21 MB, hbm ~5.5-6.5 TB/s.

#define TILE 64     // proposals per block == threads per block == one wave
#define PAD_ROW 29  // 28 floats + 1 pad; odd stride -> conflict-free on 32 banks

typedef float f32x4_v __attribute__((ext_vector_type(4)));

__global__ __launch_bounds__(64) void bucketing_bbox_wave_kernel(
    const float* __restrict__ proposals,
    const float* __restrict__ cls_preds,
    const float* __restrict__ offset_preds,
    float* __restrict__ out_bboxes,
    float* __restrict__ out_conf)
{
    __shared__ float lds[TILE * PAD_ROW];  // 7,424 B

    const int t = threadIdx.x;
    const size_t base = (size_t)blockIdx.x * TILE;   // first proposal of tile
    const size_t gid = base + t;

    // ---- Coalesced global loads: 7 float4/thread/array, lane-contiguous ----
    // ALL loads non-temporal: every input byte is consumed exactly once per
    // dispatch; allocating it in L2/L3 only saturates the IC port (measured
    // ~2.7 TB/s wall R1-R4).
    const f32x4_v* clsv = reinterpret_cast<const f32x4_v*>(cls_preds) + base * 7;
    const f32x4_v* offv = reinterpret_cast<const f32x4_v*>(offset_preds) + base * 7;
    f32x4_v creg[7], oreg[7];
#pragma unroll
    for (int k = 0; k < 7; ++k) creg[k] = __builtin_nontemporal_load(clsv + t + TILE * k);
#pragma unroll
    for (int k = 0; k < 7; ++k) oreg[k] = __builtin_nontemporal_load(offv + t + TILE * k);
    f32x4_v prv = __builtin_nontemporal_load(
        reinterpret_cast<const f32x4_v*>(proposals) + gid);

    // float4 index owned at iter k is f = t + 64k; proposal p = f/7, elem e = f%7.
    // Incremental: f += 64 => p += 9, e += 1 (64 = 9*7 + 1), wrap at 7.
    const int p0 = t / 7;
    const int e0 = t - p0 * 7;

    // ---- Phase 1: cls through LDS ----
    {
        int p = p0, e = e0;
#pragma unroll
        for (int k = 0; k < 7; ++k) {
            int a = p * PAD_ROW + 4 * e;
            lds[a + 0] = creg[k][0];
            lds[a + 1] = creg[k][1];
            lds[a + 2] = creg[k][2];
            lds[a + 3] = creg[k][3];
            p += 9; e += 1;
            if (e >= 7) { e -= 7; p += 1; }
        }
    }
    __syncthreads();  // intra-wave: hardware-released immediately

    float cls[28];
    const int rb = t * PAD_ROW;
#pragma unroll
    for (int j = 0; j < 28; ++j) cls[j] = lds[rb + j];  // stride 29: conflict-free
    __syncthreads();  // cls reads done; buffer free

    // ---- Phase 2 writes FIRST so they overlap the compute below ----
    {
        int p = p0, e = e0;
#pragma unroll
        for (int k = 0; k < 7; ++k) {
            int a = p * PAD_ROW + 4 * e;
            lds[a + 0] = oreg[k][0];
            lds[a + 1] = oreg[k][1];
            lds[a + 2] = oreg[k][2];
            lds[a + 3] = oreg[k][3];
            p += 9; e += 1;
            if (e >= 7) { e -= 7; p += 1; }
        }
    }

    // ---- top-2 per side + softmax probs + confidence (no LDS dependency) ----
    int   lab0s[4];
    float conf_sum = 0.0f;
#pragma unroll
    for (int s = 0; s < 4; ++s) {
        float best0 = cls[s * 7 + 0];
        float best1 = -INFINITY;
        int   lab0 = 0, lab1 = 0;
#pragma unroll
        for (int j = 1; j < 7; ++j) {
            float x = cls[s * 7 + j];
            bool gt0 = x > best0;
            bool gt1 = x > best1;
            // strict > with ascending j => lowest index wins ties (lax.top_k)
            best1 = gt0 ? best0 : (gt1 ? x : best1);
            lab1  = gt0 ? lab0  : (gt1 ? j : lab1);
            best0 = gt0 ? x : best0;
            lab0  = gt0 ? j : lab0;
        }
        float sum = 0.0f;
#pragma unroll
        for (int j = 0; j < 7; ++j) sum += __expf(cls[s * 7 + j] - best0);
        float inv = 1.0f / sum;
        float p0s = inv;
        float p1s = __expf(best1 - best0) * inv;

        lab0s[s] = lab0;
        float neighbor = fabsf((float)(lab0 - lab1)) - 1.0f;
        conf_sum += p0s + p1s * neighbor;
    }

    // ---- Proposal geometry (still no LDS dependency) ----
    float cx = (prv[0] + prv[2]) * 0.5f;
    float cy = (prv[1] + prv[3]) * 0.5f;
    float pw = (prv[2] - prv[0]) * 3.0f;
    float ph = (prv[3] - prv[1]) * 3.0f;
    float px1 = cx - 0.5f * pw;
    float px2 = cx + 0.5f * pw;
    float py1 = cy - 0.5f * ph;
    float py2 = cy + 0.5f * ph;
    float bw = pw / 14.0f;
    float bh = ph / 14.0f;

    __syncthreads();  // offsets staged

    float osel0 = lds[rb + 0  + lab0s[0]];
    float osel1 = lds[rb + 7  + lab0s[1]];
    float osel2 = lds[rb + 14 + lab0s[2]];
    float osel3 = lds[rb + 21 + lab0s[3]];

    float l_b = px1 + (0.5f + (float)lab0s[0]) * bw;
    float r_b = px2 - (0.5f + (float)lab0s[1]) * bw;
    float t_b = py1 + (0.5f + (float)lab0s[2]) * bh;
    float d_b = py2 - (0.5f + (float)lab0s[3]) * bh;

    float x1 = l_b - osel0 * bw;
    float x2 = r_b - osel1 * bw;
    float y1 = t_b - osel2 * bh;
    float y2 = d_b - osel3 * bh;

    const float Wm = 1332.0f;  // W - 1
    const float Hm = 799.0f;   // H - 1
    x1 = fminf(fmaxf(x1, 0.0f), Wm);
    x2 = fminf(fmaxf(x2, 0.0f), Wm);
    y1 = fminf(fmaxf(y1, 0.0f), Hm);
    y2 = fminf(fmaxf(y2, 0.0f), Hm);

    // Non-temporal stores: outputs are never re-read by this kernel.
    f32x4_v bb = {x1, y1, x2, y2};
    __builtin_nontemporal_store(bb, reinterpret_cast<f32x4_v*>(out_bboxes) + gid);
    __builtin_nontemporal_store(conf_sum * 0.25f, out_conf + gid);
}

// Tail fallback (per-thread strided; only used if total % TILE != 0 — it isn't
// for this problem's shape, but keep it correct for any size).
__global__ __launch_bounds__(256) void bucketing_bbox_tail_kernel(
    const float* __restrict__ proposals,
    const float* __restrict__ cls_preds,
    const float* __restrict__ offset_preds,
    float* __restrict__ out_bboxes,
    float* __restrict__ out_conf,
    int start, int total)
{
    int i = start + blockIdx.x * blockDim.x + threadIdx.x;
    if (i >= total) return;

    float4 pr = reinterpret_cast<const float4*>(proposals)[i];
    float cls[28], offs[28];
    {
        const float4* cp = reinterpret_cast<const float4*>(cls_preds + (size_t)i * 28);
        const float4* op = reinterpret_cast<const float4*>(offset_preds + (size_t)i * 28);
#pragma unroll
        for (int k = 0; k < 7; ++k) reinterpret_cast<float4*>(cls)[k] = cp[k];
#pragma unroll
        for (int k = 0; k < 7; ++k) reinterpret_cast<float4*>(offs)[k] = op[k];
    }
    float cx = (pr.x + pr.z) * 0.5f;
    float cy = (pr.y + pr.w) * 0.5f;
    float pw = (pr.z - pr.x) * 3.0f;
    float ph = (pr.w - pr.y) * 3.0f;
    float px1 = cx - 0.5f * pw, px2 = cx + 0.5f * pw;
    float py1 = cy - 0.5f * ph, py2 = cy + 0.5f * ph;
    float bw = pw / 14.0f, bh = ph / 14.0f;

    int lab0s[4]; float offsel[4]; float conf_sum = 0.0f;
#pragma unroll
    for (int s = 0; s < 4; ++s) {
        float best0 = cls[s * 7], best1 = -INFINITY;
        int lab0 = 0, lab1 = 0;
        float osel = offs[s * 7];
#pragma unroll
        for (int j = 1; j < 7; ++j) {
            float x = cls[s * 7 + j], o = offs[s * 7 + j];
            bool gt0 = x > best0, gt1 = x > best1;
            best1 = gt0 ? best0 : (gt1 ? x : best1);
            lab1  = gt0 ? lab0  : (gt1 ? j : lab1);
            best0 = gt0 ? x : best0;
            lab0  = gt0 ? j : lab0;
            osel  = gt0 ? o : osel;
        }
        float sum = 0.0f;
#pragma unroll
        for (int j = 0; j < 7; ++j) sum += __expf(cls[s * 7 + j] - best0);
        float inv = 1.0f / sum;
        lab0s[s] = lab0; offsel[s] = osel;
        conf_sum += inv + __expf(best1 - best0) * inv * (fabsf((float)(lab0 - lab1)) - 1.0f);
    }
    float x1 = px1 + (0.5f + (float)lab0s[0]) * bw - offsel[0] * bw;
    float x2 = px2 - (0.5f + (float)lab0s[1]) * bw - offsel[1] * bw;
    float y1 = py1 + (0.5f + (float)lab0s[2]) * bh - offsel[2] * bh;
    float y2 = py2 - (0.5f + (float)lab0s[3]) * bh - offsel[3] * bh;
    x1 = fminf(fmaxf(x1, 0.0f), 1332.0f);
    x2 = fminf(fmaxf(x2, 0.0f), 1332.0f);
    y1 = fminf(fmaxf(y1, 0.0f), 799.0f);
    y2 = fminf(fmaxf(y2, 0.0f), 799.0f);
    reinterpret_cast<float4*>(out_bboxes)[i] = make_float4(x1, y1, x2, y2);
    out_conf[i] = conf_sum * 0.25f;
}

extern "C" void kernel_launch(void* const* d_in, const int* in_sizes, int n_in,
                              void* d_out, int out_size, void* d_ws, size_t ws_size,
                              hipStream_t stream) {
    const float* proposals    = (const float*)d_in[0];
    const float* cls_preds    = (const float*)d_in[1];
    const float* offset_preds = (const float*)d_in[2];

    int total = in_sizes[0] / 4;  // B*N proposals (1,048,576)

    float* out_bboxes = (float*)d_out;                       // total*4
    float* out_conf   = (float*)d_out + (size_t)total * 4;   // total

    int full_tiles = total / TILE;   // 16,384 for this shape
    int rem = total - full_tiles * TILE;

    if (full_tiles > 0) {
        bucketing_bbox_wave_kernel<<<full_tiles, TILE, 0, stream>>>(
            proposals, cls_preds, offset_preds, out_bboxes, out_conf);
    }
    if (rem > 0) {
        int start = full_tiles * TILE;
        bucketing_bbox_tail_kernel<<<(rem + 255) / 256, 256, 0, stream>>>(
            proposals, cls_preds, offset_preds, out_bboxes, out_conf, start, total);
    }
}